// Round 1
// baseline (6505.700 us; speedup 1.0000x reference)
//
#include <hip/hip_runtime.h>
#include <cstdint>
#include <cstddef>

// Problem constants
#define NXD 512
#define NQD 512
#define NUD 128
#define NBATCH 32768
#define EPSV 1e-3f

// ---------------------------------------------------------------------------
// k_syrk: C = scale * A @ A^T + EPS*I      A: N x K row-major (lda=K), C: NxN
// 64x64 tile, 256 threads, 4x4 micro-tile
// ---------------------------------------------------------------------------
__global__ __launch_bounds__(256) void k_syrk(const float* __restrict__ A,
                                              float* __restrict__ C,
                                              int N, int K, float scale) {
  __shared__ float As[16][68];
  __shared__ float Bs[16][68];
  int tid = threadIdx.x;
  int row = tid >> 2;
  int q4 = (tid & 3) * 4;
  int tx = tid & 15, ty = tid >> 4;
  int i0 = blockIdx.x * 64, j0 = blockIdx.y * 64;
  float acc[4][4] = {};
  for (int k0 = 0; k0 < K; k0 += 16) {
    float4 a = *(const float4*)&A[(size_t)(i0 + row) * K + k0 + q4];
    float4 b = *(const float4*)&A[(size_t)(j0 + row) * K + k0 + q4];
    __syncthreads();
    As[q4 + 0][row] = a.x; As[q4 + 1][row] = a.y; As[q4 + 2][row] = a.z; As[q4 + 3][row] = a.w;
    Bs[q4 + 0][row] = b.x; Bs[q4 + 1][row] = b.y; Bs[q4 + 2][row] = b.z; Bs[q4 + 3][row] = b.w;
    __syncthreads();
#pragma unroll
    for (int kk = 0; kk < 16; ++kk) {
      float av[4], bv[4];
      *(float4*)av = *(const float4*)&As[kk][ty * 4];
      *(float4*)bv = *(const float4*)&Bs[kk][tx * 4];
#pragma unroll
      for (int i = 0; i < 4; ++i)
#pragma unroll
        for (int j = 0; j < 4; ++j) acc[i][j] += av[i] * bv[j];
    }
  }
#pragma unroll
  for (int i = 0; i < 4; ++i)
#pragma unroll
    for (int j = 0; j < 4; ++j) {
      int r = i0 + ty * 4 + i, c = j0 + tx * 4 + j;
      float v = acc[i][j] * scale;
      if (r == c) v += EPSV;
      C[(size_t)r * N + c] = v;
    }
}

// ---------------------------------------------------------------------------
// k_prep: lam, D11, C1, RHS(=[Y | -H2-Chi]) from H, Y1, Chi
// ---------------------------------------------------------------------------
__global__ void k_prep(const float* __restrict__ H, const float* __restrict__ Y1,
                       const float* __restrict__ Chi, float* __restrict__ D11,
                       float* __restrict__ C1, float* __restrict__ RHS) {
  int i = blockIdx.x;  // 0..511
  float lam = 0.5f * H[(size_t)(512 + i) * 1024 + 512 + i];
  float rlam = 1.0f / lam;
  for (int j = threadIdx.x; j < 512; j += blockDim.x) {
    float h4 = H[(size_t)(512 + i) * 1024 + 512 + j];
    D11[i * 512 + j] = (j < i) ? (-h4 * rlam) : 0.0f;
    C1[i * 512 + j] = Chi[(size_t)j * 512 + i] * rlam;
    float y = -0.5f * (H[(size_t)i * 1024 + j] + Y1[(size_t)i * 512 + j] - Y1[(size_t)j * 512 + i]);
    RHS[(size_t)i * 1024 + j] = y;
    RHS[(size_t)i * 1024 + 512 + j] = -H[(size_t)i * 1024 + 512 + j] - Chi[(size_t)i * 512 + j];
  }
}

// ---------------------------------------------------------------------------
// k_chol_diag: factor 128x128 diagonal block of P (in place, lower+diag valid)
// One block, 256 threads; each thread owns an 8x8 register tile.
// ---------------------------------------------------------------------------
__global__ __launch_bounds__(256) void k_chol_diag(float* __restrict__ P, int kb) {
  __shared__ float colbuf[2][160];
  int tid = threadIdx.x;
  int ty = tid >> 4, tx = tid & 15;
  int base = kb * 128;
  float T[8][8];
#pragma unroll
  for (int rr = 0; rr < 8; ++rr)
#pragma unroll
    for (int cc = 0; cc < 8; ++cc)
      T[rr][cc] = P[(size_t)(base + ty * 8 + rr) * 512 + base + tx * 8 + cc];

  for (int c = 0; c < 128; ++c) {
    float* cb = colbuf[c & 1];
    if (tx == (c >> 3)) {
      int cc = c & 7;
#pragma unroll
      for (int rr = 0; rr < 8; ++rr) {
        int r = ty * 8 + rr;
        cb[r + (r >> 3)] = T[rr][cc];
      }
    }
    __syncthreads();
    float dcv = cb[c + (c >> 3)];
    float dc = sqrtf(dcv);
    float rdc = 1.0f / dc;
    float rdcv = 1.0f / dcv;
    // owner finalizes column c (L values)
    if (tx == (c >> 3)) {
      int cc = c & 7;
#pragma unroll
      for (int rr = 0; rr < 8; ++rr) {
        int r = ty * 8 + rr;
        if (r == c) T[rr][cc] = dc;
        else if (r > c) T[rr][cc] *= rdc;
      }
    }
    // trailing update with raw column values: A[r][j] -= raw_r*raw_j/dcv  (r>c, j>c)
    float cr[8], cj[8];
#pragma unroll
    for (int rr = 0; rr < 8; ++rr) {
      int r = ty * 8 + rr;
      cr[rr] = (r > c) ? cb[r + (r >> 3)] * rdcv : 0.0f;
    }
#pragma unroll
    for (int cc = 0; cc < 8; ++cc) {
      int j = tx * 8 + cc;
      cj[cc] = (j > c) ? cb[j + (j >> 3)] : 0.0f;
    }
#pragma unroll
    for (int rr = 0; rr < 8; ++rr)
#pragma unroll
      for (int cc = 0; cc < 8; ++cc) T[rr][cc] -= cr[rr] * cj[cc];
    // double-buffered colbuf: next step's owner writes the other buffer, so a
    // single barrier per step suffices (the one at loop top via __syncthreads above).
  }
  __syncthreads();
#pragma unroll
  for (int rr = 0; rr < 8; ++rr)
#pragma unroll
    for (int cc = 0; cc < 8; ++cc)
      P[(size_t)(base + ty * 8 + rr) * 512 + base + tx * 8 + cc] = T[rr][cc];
}

// ---------------------------------------------------------------------------
// k_trsm: panel solve  L21 = A21 * inv(L11^T). One thread per row.
// ---------------------------------------------------------------------------
__global__ __launch_bounds__(128) void k_trsm(float* __restrict__ P, int kb) {
  __shared__ float Ls[128 * 128];
  int tid = threadIdx.x;
  int base = kb * 128;
  int i = base + 128 + blockIdx.x * 128 + tid;
  for (int idx = tid; idx < 128 * 128; idx += 128) {
    int r = idx >> 7, c = idx & 127;
    Ls[idx] = P[(size_t)(base + r) * 512 + base + c];
  }
  __syncthreads();
  float x[128];
  float* Arow = &P[(size_t)i * 512 + base];
#pragma unroll
  for (int c = 0; c < 128; ++c) {
    float a0 = Arow[c], a1 = 0.f, a2 = 0.f, a3 = 0.f;
#pragma unroll
    for (int m = 0; m < c; m += 4) {
      a0 -= x[m] * Ls[c * 128 + m];
      if (m + 1 < c) a1 -= x[m + 1] * Ls[c * 128 + m + 1];
      if (m + 2 < c) a2 -= x[m + 2] * Ls[c * 128 + m + 2];
      if (m + 3 < c) a3 -= x[m + 3] * Ls[c * 128 + m + 3];
    }
    x[c] = ((a0 + a1) + (a2 + a3)) / Ls[c * 128 + c];
  }
#pragma unroll
  for (int c = 0; c < 128; ++c) Arow[c] = x[c];
}

// ---------------------------------------------------------------------------
// k_solve_f / k_solve_b: diagonal-block triangular solves on W (512 x 1024)
// One thread per RHS column; z slice kept in registers (fully unrolled).
// ---------------------------------------------------------------------------
__global__ __launch_bounds__(256) void k_solve_f(const float* __restrict__ P,
                                                 float* __restrict__ W, int kb) {
  __shared__ float Ls[128 * 128];
  int tid = threadIdx.x;
  int base = kb * 128;
  int c = blockIdx.x * 256 + tid;
  for (int idx = tid; idx < 128 * 128; idx += 256) {
    int r = idx >> 7, m = idx & 127;
    Ls[idx] = P[(size_t)(base + r) * 512 + base + m];
  }
  __syncthreads();
  float z[128];
#pragma unroll
  for (int r = 0; r < 128; ++r) {
    float a0 = W[(size_t)(base + r) * 1024 + c], a1 = 0.f, a2 = 0.f, a3 = 0.f;
#pragma unroll
    for (int m = 0; m < r; m += 4) {
      a0 -= z[m] * Ls[r * 128 + m];
      if (m + 1 < r) a1 -= z[m + 1] * Ls[r * 128 + m + 1];
      if (m + 2 < r) a2 -= z[m + 2] * Ls[r * 128 + m + 2];
      if (m + 3 < r) a3 -= z[m + 3] * Ls[r * 128 + m + 3];
    }
    z[r] = ((a0 + a1) + (a2 + a3)) / Ls[r * 128 + r];
  }
#pragma unroll
  for (int r = 0; r < 128; ++r) W[(size_t)(base + r) * 1024 + c] = z[r];
}

__global__ __launch_bounds__(256) void k_solve_b(const float* __restrict__ P,
                                                 float* __restrict__ W, int kb) {
  __shared__ float LsT[128 * 128];  // LsT[r][m] = L[m][r]
  int tid = threadIdx.x;
  int base = kb * 128;
  int c = blockIdx.x * 256 + tid;
  for (int idx = tid; idx < 128 * 128; idx += 256) {
    int r = idx >> 7, m = idx & 127;
    LsT[idx] = P[(size_t)(base + m) * 512 + base + r];
  }
  __syncthreads();
  float z[128];
#pragma unroll
  for (int rr = 0; rr < 128; ++rr) {
    int r = 127 - rr;
    float a0 = W[(size_t)(base + r) * 1024 + c], a1 = 0.f, a2 = 0.f, a3 = 0.f;
#pragma unroll
    for (int m = r + 1; m < 128; m += 4) {
      a0 -= z[m] * LsT[r * 128 + m];
      if (m + 1 < 128) a1 -= z[m + 1] * LsT[r * 128 + m + 1];
      if (m + 2 < 128) a2 -= z[m + 2] * LsT[r * 128 + m + 2];
      if (m + 3 < 128) a3 -= z[m + 3] * LsT[r * 128 + m + 3];
    }
    z[r] = ((a0 + a1) + (a2 + a3)) / LsT[r * 128 + r];
  }
#pragma unroll
  for (int r = 0; r < 128; ++r) W[(size_t)(base + r) * 1024 + c] = z[r];
}

// ---------------------------------------------------------------------------
// k_gemm_acc<TA,TB>: C[ci0+i][cj0+j] -= sum_k Aop[i][k] * Bop[k][j]
//   Aop[i][k] = TA ? A[(k0+k)*lda + ai0+i] : A[(ai0+i)*lda + k0+k]
//   Bop[k][j] = TB ? B[(bj0+j)*ldb + k0+k] : B[(k0+k)*ldb + bj0+j]
// ---------------------------------------------------------------------------
template <int TA, int TB>
__global__ __launch_bounds__(256) void k_gemm_acc(float* __restrict__ C, int ldc,
                                                  int ci0, int cj0,
                                                  const float* __restrict__ A, int lda, int ai0,
                                                  const float* __restrict__ B, int ldb, int bj0,
                                                  int k0, int K) {
  __shared__ float As[16][68];
  __shared__ float Bs[16][68];
  int tid = threadIdx.x;
  int tx = tid & 15, ty = tid >> 4;
  int i0 = blockIdx.x * 64, j0 = blockIdx.y * 64;
  float acc[4][4] = {};
  for (int kc = 0; kc < K; kc += 16) {
    float4 av, bv;
    if (TA == 0) {
      int row = tid >> 2, q4 = (tid & 3) * 4;
      av = *(const float4*)&A[(size_t)(ai0 + i0 + row) * lda + k0 + kc + q4];
    } else {
      int kr = tid >> 4, m4 = (tid & 15) * 4;
      av = *(const float4*)&A[(size_t)(k0 + kc + kr) * lda + ai0 + i0 + m4];
    }
    if (TB == 0) {
      int kr = tid >> 4, j4 = (tid & 15) * 4;
      bv = *(const float4*)&B[(size_t)(k0 + kc + kr) * ldb + bj0 + j0 + j4];
    } else {
      int row = tid >> 2, q4 = (tid & 3) * 4;
      bv = *(const float4*)&B[(size_t)(bj0 + j0 + row) * ldb + k0 + kc + q4];
    }
    __syncthreads();
    if (TA == 0) {
      int row = tid >> 2, q4 = (tid & 3) * 4;
      As[q4 + 0][row] = av.x; As[q4 + 1][row] = av.y; As[q4 + 2][row] = av.z; As[q4 + 3][row] = av.w;
    } else {
      int kr = tid >> 4, m4 = (tid & 15) * 4;
      *(float4*)&As[kr][m4] = av;
    }
    if (TB == 0) {
      int kr = tid >> 4, j4 = (tid & 15) * 4;
      *(float4*)&Bs[kr][j4] = bv;
    } else {
      int row = tid >> 2, q4 = (tid & 3) * 4;
      Bs[q4 + 0][row] = bv.x; Bs[q4 + 1][row] = bv.y; Bs[q4 + 2][row] = bv.z; Bs[q4 + 3][row] = bv.w;
    }
    __syncthreads();
#pragma unroll
    for (int kk = 0; kk < 16; ++kk) {
      float a4[4], b4[4];
      *(float4*)a4 = *(const float4*)&As[kk][ty * 4];
      *(float4*)b4 = *(const float4*)&Bs[kk][tx * 4];
#pragma unroll
      for (int i = 0; i < 4; ++i)
#pragma unroll
        for (int j = 0; j < 4; ++j) acc[i][j] += a4[i] * b4[j];
    }
  }
#pragma unroll
  for (int i = 0; i < 4; ++i)
#pragma unroll
    for (int j = 0; j < 4; ++j)
      C[(size_t)(ci0 + i0 + ty * 4 + i) * ldc + cj0 + j0 + tx * 4 + j] -= acc[i][j];
}

// ---------------------------------------------------------------------------
// k_bgemm: C[b][n] = sum over up-to-3 segments of  S[b][k] * W[n][k]
// (row-of-S dot row-of-W).  64x64 tile, 256 threads, 4x4 micro-tile.
// ---------------------------------------------------------------------------
__global__ __launch_bounds__(256) void k_bgemm(
    const float* __restrict__ s0, int ld0, const float* __restrict__ w0, int lw0, int K0,
    const float* __restrict__ s1, int ld1, const float* __restrict__ w1, int lw1, int K1,
    const float* __restrict__ s2, int ld2, const float* __restrict__ w2, int lw2, int K2,
    float* __restrict__ C, int N) {
  __shared__ float As[16][68];
  __shared__ float Bs[16][68];
  int tid = threadIdx.x;
  int row = tid >> 2;
  int q4 = (tid & 3) * 4;
  int tx = tid & 15, ty = tid >> 4;
  size_t i0 = (size_t)blockIdx.x * 64;
  int j0 = blockIdx.y * 64;
  float acc[4][4] = {};
#pragma unroll
  for (int seg = 0; seg < 3; ++seg) {
    const float* S = (seg == 0) ? s0 : (seg == 1) ? s1 : s2;
    const float* W = (seg == 0) ? w0 : (seg == 1) ? w1 : w2;
    int ld = (seg == 0) ? ld0 : (seg == 1) ? ld1 : ld2;
    int lw = (seg == 0) ? lw0 : (seg == 1) ? lw1 : lw2;
    int K = (seg == 0) ? K0 : (seg == 1) ? K1 : K2;
    for (int k0 = 0; k0 < K; k0 += 16) {
      float4 a = *(const float4*)&S[(i0 + row) * ld + k0 + q4];
      float4 b = *(const float4*)&W[(size_t)(j0 + row) * lw + k0 + q4];
      __syncthreads();
      As[q4 + 0][row] = a.x; As[q4 + 1][row] = a.y; As[q4 + 2][row] = a.z; As[q4 + 3][row] = a.w;
      Bs[q4 + 0][row] = b.x; Bs[q4 + 1][row] = b.y; Bs[q4 + 2][row] = b.z; Bs[q4 + 3][row] = b.w;
      __syncthreads();
#pragma unroll
      for (int kk = 0; kk < 16; ++kk) {
        float a4[4], b4[4];
        *(float4*)a4 = *(const float4*)&As[kk][ty * 4];
        *(float4*)b4 = *(const float4*)&Bs[kk][tx * 4];
#pragma unroll
        for (int i = 0; i < 4; ++i)
#pragma unroll
          for (int j = 0; j < 4; ++j) acc[i][j] += a4[i] * b4[j];
      }
    }
  }
#pragma unroll
  for (int i = 0; i < 4; ++i)
#pragma unroll
    for (int j = 0; j < 4; ++j)
      C[(i0 + ty * 4 + i) * N + j0 + tx * 4 + j] = acc[i][j];
}

// ---------------------------------------------------------------------------
// k_scan: per-row recurrence  w[b,i] = tanh(base[b,i] + sum_{j<i} w[b,j]*D11[i,j])
// 32 rows per block, 512 threads (16 lanes per row, wave-synchronous: no
// __syncthreads in the 512-step loop).  w tile in LDS (64 KB), XOR-swizzled
// so both the stride-16 reads and the writes are <=2-way bank conflicts.
// ---------------------------------------------------------------------------
__global__ __launch_bounds__(512) void k_scan(const float* __restrict__ basep,
                                              const float* __restrict__ D11,
                                              float* __restrict__ wout) {
  __shared__ float wls[32 * 512];
  int tid = threadIdx.x;
  int l = tid & 63;
  int wv = tid >> 6;          // wave 0..7
  int rb = l >> 4;            // row-in-wave 0..3
  int t = l & 15;             // sub-lane 0..15
  int b = wv * 4 + rb;        // tile row 0..31
  size_t gb = (size_t)blockIdx.x * 32 + b;
  const float* brow = basep + gb * 512;
  float* wbase = &wls[b * 512];
  int sw = rb << 4;           // xor swizzle (b&3)<<4

  for (int i = 0; i < 512; ++i) {
    float p = 0.0f;
    int cnt = (i - t + 15) >> 4;   // #m with 16m+t < i
    if (i <= t) cnt = 0;
    for (int m = 0; m < cnt; ++m) {
      int j = 16 * m + t;
      p += wbase[j ^ sw] * D11[i * 512 + j];
    }
    p += __shfl_down(p, 8);
    p += __shfl_down(p, 4);
    p += __shfl_down(p, 2);
    p += __shfl_down(p, 1);
    if (t == 0) wbase[i ^ sw] = tanhf(brow[i] + p);
    // same-wave LDS RAW: DS ops of a wave complete in order; no barrier needed.
  }
  // copy out: each wave writes its own 4 rows (coalesced)
  for (int r = 0; r < 4; ++r) {
    int bb = wv * 4 + r;
    size_t g = (size_t)blockIdx.x * 32 + bb;
    int sw2 = r << 4;
    for (int j = l; j < 512; j += 64) wout[g * 512 + j] = wls[bb * 512 + (j ^ sw2)];
  }
}

// ---------------------------------------------------------------------------
extern "C" void kernel_launch(void* const* d_in, const int* in_sizes, int n_in,
                              void* d_out, int out_size, void* d_ws, size_t ws_size,
                              hipStream_t stream) {
  const float* xi = (const float*)d_in[1];
  const float* u = (const float*)d_in[2];
  const float* Pstar = (const float*)d_in[3];
  const float* Chi = (const float*)d_in[4];
  const float* Y1 = (const float*)d_in[5];
  const float* B2 = (const float*)d_in[6];
  const float* D12 = (const float*)d_in[7];
  const float* X = (const float*)d_in[8];
  float* out = (float*)d_out;

  float* ws = (float*)d_ws;
  float* Wscan = ws;                              // B x NQ   (scan output w)
  float* H = Wscan + (size_t)NBATCH * NQD;        // 1024 x 1024
  float* Pm = H + 1024 * 1024;                    // 512 x 512 (P, then L)
  float* D11 = Pm + 512 * 512;                    // 512 x 512
  float* C1 = D11 + 512 * 512;                    // 512 x 512
  float* Wm = C1 + 512 * 512;                     // 512 x 1024 (RHS -> [A | B1])

  // ---- small-matrix stage ----
  k_syrk<<<dim3(16, 16), 256, 0, stream>>>(X, H, 1024, 1024, 1.0f);
  k_syrk<<<dim3(8, 8), 256, 0, stream>>>(Pstar, Pm, 512, 512, 0.5f);
  k_prep<<<512, 256, 0, stream>>>(H, Y1, Chi, D11, C1, Wm);

  // Cholesky P = L L^T (blocked, NB=128)
  for (int kb = 0; kb < 4; ++kb) {
    k_chol_diag<<<1, 256, 0, stream>>>(Pm, kb);
    int rem = 512 - (kb + 1) * 128;
    if (rem > 0) {
      k_trsm<<<rem / 128, 128, 0, stream>>>(Pm, kb);
      k_gemm_acc<0, 1><<<dim3(rem / 64, rem / 64), 256, 0, stream>>>(
          Pm, 512, (kb + 1) * 128, (kb + 1) * 128,
          Pm, 512, (kb + 1) * 128,
          Pm, 512, (kb + 1) * 128, kb * 128, 128);
    }
  }
  // forward solve L Z = RHS
  for (int kb = 0; kb < 4; ++kb) {
    k_solve_f<<<4, 256, 0, stream>>>(Pm, Wm, kb);
    int rem = 512 - (kb + 1) * 128;
    if (rem > 0)
      k_gemm_acc<0, 0><<<dim3(rem / 64, 16), 256, 0, stream>>>(
          Wm, 1024, (kb + 1) * 128, 0,
          Pm, 512, (kb + 1) * 128,
          Wm, 1024, 0, kb * 128, 128);
  }
  // backward solve L^T W = Z   ->  Wm = [A | B1]
  for (int kb = 3; kb >= 0; --kb) {
    k_solve_b<<<4, 256, 0, stream>>>(Pm, Wm, kb);
    if (kb > 0)
      k_gemm_acc<1, 0><<<dim3(kb * 128 / 64, 16), 256, 0, stream>>>(
          Wm, 1024, 0, 0,
          Pm, 512, 0,
          Wm, 1024, 0, kb * 128, 128);
  }

  // ---- big stage ----
  // base = xi @ C1^T + u @ D12^T   (stored in d_out as scratch)
  k_bgemm<<<dim3(NBATCH / 64, NQD / 64), 256, 0, stream>>>(
      xi, NXD, C1, NXD, NXD,
      u, NUD, D12, NUD, NUD,
      xi, NXD, C1, NXD, 0,
      out, NQD);
  // sequential tanh recurrence -> Wscan
  k_scan<<<NBATCH / 32, 512, 0, stream>>>(out, D11, Wscan);
  // xi_ = xi @ A^T + w @ B1^T + u @ B2^T
  k_bgemm<<<dim3(NBATCH / 64, NXD / 64), 256, 0, stream>>>(
      xi, NXD, Wm, 1024, NXD,
      Wscan, NQD, Wm + 512, 1024, NQD,
      u, NUD, B2, NUD, NUD,
      out, NXD);
}

// Round 2
// 5777.510 us; speedup vs baseline: 1.1260x; 1.1260x over previous
//
#include <hip/hip_runtime.h>
#include <hip/hip_bf16.h>
#include <cstdint>
#include <cstddef>

// Problem constants
#define NXD 512
#define NQD 512
#define NUD 128
#define NBATCH 32768
#define EPSV 1e-3f
#define KBASE 640   // [xi | u]
#define KFIN 1152   // [xi | u | w]

typedef unsigned short u16;
typedef short bf16x8 __attribute__((ext_vector_type(8)));
typedef float f32x4 __attribute__((ext_vector_type(4)));

__device__ __forceinline__ void gload_lds16(const u16* g, u16* l) {
  __builtin_amdgcn_global_load_lds((const __attribute__((address_space(1))) void*)g,
                                   (__attribute__((address_space(3))) void*)l, 16, 0, 0);
}

// ---------------------------------------------------------------------------
// k_syrk: C = scale * A @ A^T + EPS*I      A: N x K row-major (lda=K), C: NxN
// ---------------------------------------------------------------------------
__global__ __launch_bounds__(256) void k_syrk(const float* __restrict__ A,
                                              float* __restrict__ C,
                                              int N, int K, float scale) {
  __shared__ float As[16][68];
  __shared__ float Bs[16][68];
  int tid = threadIdx.x;
  int row = tid >> 2;
  int q4 = (tid & 3) * 4;
  int tx = tid & 15, ty = tid >> 4;
  int i0 = blockIdx.x * 64, j0 = blockIdx.y * 64;
  float acc[4][4] = {};
  for (int k0 = 0; k0 < K; k0 += 16) {
    float4 a = *(const float4*)&A[(size_t)(i0 + row) * K + k0 + q4];
    float4 b = *(const float4*)&A[(size_t)(j0 + row) * K + k0 + q4];
    __syncthreads();
    As[q4 + 0][row] = a.x; As[q4 + 1][row] = a.y; As[q4 + 2][row] = a.z; As[q4 + 3][row] = a.w;
    Bs[q4 + 0][row] = b.x; Bs[q4 + 1][row] = b.y; Bs[q4 + 2][row] = b.z; Bs[q4 + 3][row] = b.w;
    __syncthreads();
#pragma unroll
    for (int kk = 0; kk < 16; ++kk) {
      float av[4], bv[4];
      *(float4*)av = *(const float4*)&As[kk][ty * 4];
      *(float4*)bv = *(const float4*)&Bs[kk][tx * 4];
#pragma unroll
      for (int i = 0; i < 4; ++i)
#pragma unroll
        for (int j = 0; j < 4; ++j) acc[i][j] += av[i] * bv[j];
    }
  }
#pragma unroll
  for (int i = 0; i < 4; ++i)
#pragma unroll
    for (int j = 0; j < 4; ++j) {
      int r = i0 + ty * 4 + i, c = j0 + tx * 4 + j;
      float v = acc[i][j] * scale;
      if (r == c) v += EPSV;
      C[(size_t)r * N + c] = v;
    }
}

// ---------------------------------------------------------------------------
// k_prep: lam, D11, C1, RHS(=[Y | -H2-Chi]) from H, Y1, Chi
// ---------------------------------------------------------------------------
__global__ void k_prep(const float* __restrict__ H, const float* __restrict__ Y1,
                       const float* __restrict__ Chi, float* __restrict__ D11,
                       float* __restrict__ C1, float* __restrict__ RHS) {
  int i = blockIdx.x;  // 0..511
  float lam = 0.5f * H[(size_t)(512 + i) * 1024 + 512 + i];
  float rlam = 1.0f / lam;
  for (int j = threadIdx.x; j < 512; j += blockDim.x) {
    float h4 = H[(size_t)(512 + i) * 1024 + 512 + j];
    D11[i * 512 + j] = (j < i) ? (-h4 * rlam) : 0.0f;
    C1[i * 512 + j] = Chi[(size_t)j * 512 + i] * rlam;
    float y = -0.5f * (H[(size_t)i * 1024 + j] + Y1[(size_t)i * 512 + j] - Y1[(size_t)j * 512 + i]);
    RHS[(size_t)i * 1024 + j] = y;
    RHS[(size_t)i * 1024 + 512 + j] = -H[(size_t)i * 1024 + 512 + j] - Chi[(size_t)i * 512 + j];
  }
}

// ---------------------------------------------------------------------------
// k_chol_diag: factor 128x128 diagonal block of P in place
// ---------------------------------------------------------------------------
__global__ __launch_bounds__(256) void k_chol_diag(float* __restrict__ P, int kb) {
  __shared__ float colbuf[2][160];
  int tid = threadIdx.x;
  int ty = tid >> 4, tx = tid & 15;
  int base = kb * 128;
  float T[8][8];
#pragma unroll
  for (int rr = 0; rr < 8; ++rr)
#pragma unroll
    for (int cc = 0; cc < 8; ++cc)
      T[rr][cc] = P[(size_t)(base + ty * 8 + rr) * 512 + base + tx * 8 + cc];

  for (int c = 0; c < 128; ++c) {
    float* cb = colbuf[c & 1];
    if (tx == (c >> 3)) {
      int cc = c & 7;
#pragma unroll
      for (int rr = 0; rr < 8; ++rr) {
        int r = ty * 8 + rr;
        cb[r + (r >> 3)] = T[rr][cc];
      }
    }
    __syncthreads();
    float dcv = cb[c + (c >> 3)];
    float dc = sqrtf(dcv);
    float rdc = 1.0f / dc;
    float rdcv = 1.0f / dcv;
    if (tx == (c >> 3)) {
      int cc = c & 7;
#pragma unroll
      for (int rr = 0; rr < 8; ++rr) {
        int r = ty * 8 + rr;
        if (r == c) T[rr][cc] = dc;
        else if (r > c) T[rr][cc] *= rdc;
      }
    }
    float cr[8], cj[8];
#pragma unroll
    for (int rr = 0; rr < 8; ++rr) {
      int r = ty * 8 + rr;
      cr[rr] = (r > c) ? cb[r + (r >> 3)] * rdcv : 0.0f;
    }
#pragma unroll
    for (int cc = 0; cc < 8; ++cc) {
      int j = tx * 8 + cc;
      cj[cc] = (j > c) ? cb[j + (j >> 3)] : 0.0f;
    }
#pragma unroll
    for (int rr = 0; rr < 8; ++rr)
#pragma unroll
      for (int cc = 0; cc < 8; ++cc) T[rr][cc] -= cr[rr] * cj[cc];
  }
  __syncthreads();
#pragma unroll
  for (int rr = 0; rr < 8; ++rr)
#pragma unroll
    for (int cc = 0; cc < 8; ++cc)
      P[(size_t)(base + ty * 8 + rr) * 512 + base + tx * 8 + cc] = T[rr][cc];
}

// ---------------------------------------------------------------------------
// k_trsm: panel solve  L21 = A21 * inv(L11^T). One thread per row.
// ---------------------------------------------------------------------------
__global__ __launch_bounds__(128) void k_trsm(float* __restrict__ P, int kb) {
  __shared__ float Ls[128 * 128];
  int tid = threadIdx.x;
  int base = kb * 128;
  int i = base + 128 + blockIdx.x * 128 + tid;
  for (int idx = tid; idx < 128 * 128; idx += 128) {
    int r = idx >> 7, c = idx & 127;
    Ls[idx] = P[(size_t)(base + r) * 512 + base + c];
  }
  __syncthreads();
  float x[128];
  float* Arow = &P[(size_t)i * 512 + base];
#pragma unroll
  for (int c = 0; c < 128; ++c) {
    float a0 = Arow[c], a1 = 0.f, a2 = 0.f, a3 = 0.f;
#pragma unroll
    for (int m = 0; m < c; m += 4) {
      a0 -= x[m] * Ls[c * 128 + m];
      if (m + 1 < c) a1 -= x[m + 1] * Ls[c * 128 + m + 1];
      if (m + 2 < c) a2 -= x[m + 2] * Ls[c * 128 + m + 2];
      if (m + 3 < c) a3 -= x[m + 3] * Ls[c * 128 + m + 3];
    }
    x[c] = ((a0 + a1) + (a2 + a3)) / Ls[c * 128 + c];
  }
#pragma unroll
  for (int c = 0; c < 128; ++c) Arow[c] = x[c];
}

// ---------------------------------------------------------------------------
// k_solve_f / k_solve_b: diagonal-block triangular solves on W (512 x 1024)
// ---------------------------------------------------------------------------
__global__ __launch_bounds__(256) void k_solve_f(const float* __restrict__ P,
                                                 float* __restrict__ W, int kb) {
  __shared__ float Ls[128 * 128];
  int tid = threadIdx.x;
  int base = kb * 128;
  int c = blockIdx.x * 256 + tid;
  for (int idx = tid; idx < 128 * 128; idx += 256) {
    int r = idx >> 7, m = idx & 127;
    Ls[idx] = P[(size_t)(base + r) * 512 + base + m];
  }
  __syncthreads();
  float z[128];
#pragma unroll
  for (int r = 0; r < 128; ++r) {
    float a0 = W[(size_t)(base + r) * 1024 + c], a1 = 0.f, a2 = 0.f, a3 = 0.f;
#pragma unroll
    for (int m = 0; m < r; m += 4) {
      a0 -= z[m] * Ls[r * 128 + m];
      if (m + 1 < r) a1 -= z[m + 1] * Ls[r * 128 + m + 1];
      if (m + 2 < r) a2 -= z[m + 2] * Ls[r * 128 + m + 2];
      if (m + 3 < r) a3 -= z[m + 3] * Ls[r * 128 + m + 3];
    }
    z[r] = ((a0 + a1) + (a2 + a3)) / Ls[r * 128 + r];
  }
#pragma unroll
  for (int r = 0; r < 128; ++r) W[(size_t)(base + r) * 1024 + c] = z[r];
}

__global__ __launch_bounds__(256) void k_solve_b(const float* __restrict__ P,
                                                 float* __restrict__ W, int kb) {
  __shared__ float LsT[128 * 128];
  int tid = threadIdx.x;
  int base = kb * 128;
  int c = blockIdx.x * 256 + tid;
  for (int idx = tid; idx < 128 * 128; idx += 256) {
    int r = idx >> 7, m = idx & 127;
    LsT[idx] = P[(size_t)(base + m) * 512 + base + r];
  }
  __syncthreads();
  float z[128];
#pragma unroll
  for (int rr = 0; rr < 128; ++rr) {
    int r = 127 - rr;
    float a0 = W[(size_t)(base + r) * 1024 + c], a1 = 0.f, a2 = 0.f, a3 = 0.f;
#pragma unroll
    for (int m = r + 1; m < 128; m += 4) {
      a0 -= z[m] * LsT[r * 128 + m];
      if (m + 1 < 128) a1 -= z[m + 1] * LsT[r * 128 + m + 1];
      if (m + 2 < 128) a2 -= z[m + 2] * LsT[r * 128 + m + 2];
      if (m + 3 < 128) a3 -= z[m + 3] * LsT[r * 128 + m + 3];
    }
    z[r] = ((a0 + a1) + (a2 + a3)) / LsT[r * 128 + r];
  }
#pragma unroll
  for (int r = 0; r < 128; ++r) W[(size_t)(base + r) * 1024 + c] = z[r];
}

// ---------------------------------------------------------------------------
// k_gemm_acc<TA,TB>: C -= Aop @ Bop (trailing updates, fp32, small matrices)
// ---------------------------------------------------------------------------
template <int TA, int TB>
__global__ __launch_bounds__(256) void k_gemm_acc(float* __restrict__ C, int ldc,
                                                  int ci0, int cj0,
                                                  const float* __restrict__ A, int lda, int ai0,
                                                  const float* __restrict__ B, int ldb, int bj0,
                                                  int k0, int K) {
  __shared__ float As[16][68];
  __shared__ float Bs[16][68];
  int tid = threadIdx.x;
  int tx = tid & 15, ty = tid >> 4;
  int i0 = blockIdx.x * 64, j0 = blockIdx.y * 64;
  float acc[4][4] = {};
  for (int kc = 0; kc < K; kc += 16) {
    float4 av, bv;
    if (TA == 0) {
      int row = tid >> 2, q4 = (tid & 3) * 4;
      av = *(const float4*)&A[(size_t)(ai0 + i0 + row) * lda + k0 + kc + q4];
    } else {
      int kr = tid >> 4, m4 = (tid & 15) * 4;
      av = *(const float4*)&A[(size_t)(k0 + kc + kr) * lda + ai0 + i0 + m4];
    }
    if (TB == 0) {
      int kr = tid >> 4, j4 = (tid & 15) * 4;
      bv = *(const float4*)&B[(size_t)(k0 + kc + kr) * ldb + bj0 + j0 + j4];
    } else {
      int row = tid >> 2, q4 = (tid & 3) * 4;
      bv = *(const float4*)&B[(size_t)(bj0 + j0 + row) * ldb + k0 + kc + q4];
    }
    __syncthreads();
    if (TA == 0) {
      int row = tid >> 2, q4 = (tid & 3) * 4;
      As[q4 + 0][row] = av.x; As[q4 + 1][row] = av.y; As[q4 + 2][row] = av.z; As[q4 + 3][row] = av.w;
    } else {
      int kr = tid >> 4, m4 = (tid & 15) * 4;
      *(float4*)&As[kr][m4] = av;
    }
    if (TB == 0) {
      int kr = tid >> 4, j4 = (tid & 15) * 4;
      *(float4*)&Bs[kr][j4] = bv;
    } else {
      int row = tid >> 2, q4 = (tid & 3) * 4;
      Bs[q4 + 0][row] = bv.x; Bs[q4 + 1][row] = bv.y; Bs[q4 + 2][row] = bv.z; Bs[q4 + 3][row] = bv.w;
    }
    __syncthreads();
#pragma unroll
    for (int kk = 0; kk < 16; ++kk) {
      float a4[4], b4[4];
      *(float4*)a4 = *(const float4*)&As[kk][ty * 4];
      *(float4*)b4 = *(const float4*)&Bs[kk][tx * 4];
#pragma unroll
      for (int i = 0; i < 4; ++i)
#pragma unroll
        for (int j = 0; j < 4; ++j) acc[i][j] += a4[i] * b4[j];
    }
  }
#pragma unroll
  for (int i = 0; i < 4; ++i)
#pragma unroll
    for (int j = 0; j < 4; ++j)
      C[(size_t)(ci0 + i0 + ty * 4 + i) * ldc + cj0 + j0 + tx * 4 + j] -= acc[i][j];
}

// ---------------------------------------------------------------------------
// k_pack_z: Zb[b][0:512) = bf16(xi[b]), Zb[b][512:640) = bf16(u[b])
// ---------------------------------------------------------------------------
__global__ __launch_bounds__(256) void k_pack_z(const float* __restrict__ xi,
                                                const float* __restrict__ u,
                                                __hip_bfloat16* __restrict__ Zb) {
  size_t b = blockIdx.x;
  for (int c = threadIdx.x; c < KBASE; c += 256) {
    float v = (c < 512) ? xi[b * 512 + c] : u[b * 128 + (c - 512)];
    Zb[b * KFIN + c] = __float2bfloat16(v);
  }
}

// ---------------------------------------------------------------------------
// k_pack_w: Wbase[n] = [C1[n,:] | D12[n,:]]  (512 x 640)
//           Wfin[n]  = [A[n,:] | B2[n,:] | B1[n,:]]  (512 x 1152)
//           A,B1 come from Wm (512 x 1024 = [A | B1])
// ---------------------------------------------------------------------------
__global__ __launch_bounds__(256) void k_pack_w(const float* __restrict__ C1,
                                                const float* __restrict__ D12,
                                                const float* __restrict__ Wm,
                                                const float* __restrict__ B2,
                                                __hip_bfloat16* __restrict__ Wbase,
                                                __hip_bfloat16* __restrict__ Wfin) {
  int n = blockIdx.x;
  for (int c = threadIdx.x; c < KBASE; c += 256) {
    float v = (c < 512) ? C1[(size_t)n * 512 + c] : D12[(size_t)n * 128 + (c - 512)];
    Wbase[(size_t)n * KBASE + c] = __float2bfloat16(v);
  }
  for (int c = threadIdx.x; c < KFIN; c += 256) {
    float v;
    if (c < 512) v = Wm[(size_t)n * 1024 + c];                 // A
    else if (c < 640) v = B2[(size_t)n * 128 + (c - 512)];     // B2
    else v = Wm[(size_t)n * 1024 + 512 + (c - 640)];           // B1
    Wfin[(size_t)n * KFIN + c] = __float2bfloat16(v);
  }
}

// ---------------------------------------------------------------------------
// k_gemm_bf16: C[m][n] = sum_k Z[m][k] * W[n][k]   (both K-contiguous rows)
// 128x128 tile, BK=32, 256 threads = 4 waves in 2x2, 16x16x32 bf16 MFMA.
// global_load_lds width=16 staging; XOR-swizzled LDS chunks so the
// fragment ds_read_b128s are 2-way (free) bank aliasing.
// LDS slot s of row r holds global chunk s ^ sigma(r), sigma(r)=(r^(r>>2))&3.
// ---------------------------------------------------------------------------
__global__ __launch_bounds__(256) void k_gemm_bf16(
    const u16* __restrict__ Z, int ldz,
    const u16* __restrict__ W, int ldw,
    float* __restrict__ C, int N, int K) {
  __shared__ u16 As[128 * 32];
  __shared__ u16 Bs[128 * 32];
  int tid = threadIdx.x;
  int l = tid & 63, wv = tid >> 6;
  size_t m0 = (size_t)blockIdx.x * 128;
  int n0 = blockIdx.y * 128;

  // staging: wave wv, lane l covers (row = base + l>>2, lds slot = l&3),
  // global chunk = (l&3) ^ sigma(row) with sigma = ((l>>2)&3) ^ (l>>4)
  int ra = wv * 16 + (l >> 2);
  int gq = (l & 3) ^ ((l >> 2) & 3) ^ (l >> 4);
  const u16* ga0 = Z + (m0 + ra) * (size_t)ldz + gq * 8;
  const u16* ga1 = Z + (m0 + ra + 64) * (size_t)ldz + gq * 8;
  const u16* gb0 = W + (size_t)(n0 + ra) * ldw + gq * 8;
  const u16* gb1 = W + (size_t)(n0 + ra + 64) * ldw + gq * 8;
  u16* la0 = &As[wv * 512];
  u16* la1 = &As[2048 + wv * 512];
  u16* lb0 = &Bs[wv * 512];
  u16* lb1 = &Bs[2048 + wv * 512];

  // fragment read offsets: row = T0 + (l&15), slot s = (l>>4) ^ (l&3) ^ ((l>>2)&3)
  int wm = (wv & 1) * 64, wn = (wv >> 1) * 64;
  int fr = l & 15;
  int fs = (l >> 4) ^ (l & 3) ^ ((l >> 2) & 3);
  int offa[4], offb[4];
#pragma unroll
  for (int t = 0; t < 4; ++t) {
    offa[t] = (wm + t * 16 + fr) * 32 + fs * 8;
    offb[t] = (wn + t * 16 + fr) * 32 + fs * 8;
  }

  f32x4 acc[4][4] = {};
  for (int k0 = 0; k0 < K; k0 += 32) {
    __syncthreads();  // previous stage's LDS reads done
    gload_lds16(ga0, la0);
    gload_lds16(ga1, la1);
    gload_lds16(gb0, lb0);
    gload_lds16(gb1, lb1);
    ga0 += 32; ga1 += 32; gb0 += 32; gb1 += 32;
    __syncthreads();  // staging complete
    bf16x8 af[4], bfr[4];
#pragma unroll
    for (int t = 0; t < 4; ++t) {
      af[t] = *(const bf16x8*)&As[offa[t]];
      bfr[t] = *(const bf16x8*)&Bs[offb[t]];
    }
#pragma unroll
    for (int mt = 0; mt < 4; ++mt)
#pragma unroll
      for (int nt = 0; nt < 4; ++nt)
        acc[mt][nt] = __builtin_amdgcn_mfma_f32_16x16x32_bf16(af[mt], bfr[nt], acc[mt][nt], 0, 0, 0);
  }

  // epilogue: C/D layout col = l&15, row = (l>>4)*4 + reg
#pragma unroll
  for (int mt = 0; mt < 4; ++mt)
#pragma unroll
    for (int nt = 0; nt < 4; ++nt) {
      int ncol = n0 + wn + nt * 16 + (l & 15);
#pragma unroll
      for (int r = 0; r < 4; ++r) {
        size_t mrow = m0 + wm + mt * 16 + (l >> 4) * 4 + r;
        C[mrow * N + ncol] = acc[mt][nt][r];
      }
    }
}

// ---------------------------------------------------------------------------
// k_scan: w[b,i] = tanh(base[b,i] + sum_{j<i} w[b,j]*D11[i,j])
// 32 rows/block, 512 threads, wave-synchronous (16 lanes per row).
// Writes w in bf16 into Z's w-column block (stride KFIN).
// ---------------------------------------------------------------------------
__global__ __launch_bounds__(512) void k_scan(const float* __restrict__ basep,
                                              const float* __restrict__ D11,
                                              __hip_bfloat16* __restrict__ zw) {
  __shared__ float wls[32 * 512];
  int tid = threadIdx.x;
  int l = tid & 63;
  int wv = tid >> 6;
  int rb = l >> 4;
  int t = l & 15;
  int b = wv * 4 + rb;
  size_t gb = (size_t)blockIdx.x * 32 + b;
  const float* brow = basep + gb * 512;
  float* wbase = &wls[b * 512];
  int sw = rb << 4;

  for (int i = 0; i < 512; ++i) {
    float p = 0.0f;
    int cnt = (i - t + 15) >> 4;
    if (i <= t) cnt = 0;
    for (int m = 0; m < cnt; ++m) {
      int j = 16 * m + t;
      p += wbase[j ^ sw] * D11[i * 512 + j];
    }
    p += __shfl_down(p, 8);
    p += __shfl_down(p, 4);
    p += __shfl_down(p, 2);
    p += __shfl_down(p, 1);
    if (t == 0) wbase[i ^ sw] = tanhf(brow[i] + p);
  }
  for (int r = 0; r < 4; ++r) {
    int bb = wv * 4 + r;
    size_t g = (size_t)blockIdx.x * 32 + bb;
    int sw2 = r << 4;
    for (int j = l; j < 512; j += 64)
      zw[g * KFIN + j] = __float2bfloat16(wls[bb * 512 + (j ^ sw2)]);
  }
}

// ---------------------------------------------------------------------------
extern "C" void kernel_launch(void* const* d_in, const int* in_sizes, int n_in,
                              void* d_out, int out_size, void* d_ws, size_t ws_size,
                              hipStream_t stream) {
  const float* xi = (const float*)d_in[1];
  const float* u = (const float*)d_in[2];
  const float* Pstar = (const float*)d_in[3];
  const float* Chi = (const float*)d_in[4];
  const float* Y1 = (const float*)d_in[5];
  const float* B2 = (const float*)d_in[6];
  const float* D12 = (const float*)d_in[7];
  const float* X = (const float*)d_in[8];
  float* out = (float*)d_out;

  char* ws = (char*)d_ws;
  __hip_bfloat16* Zb = (__hip_bfloat16*)ws;                       // 32768 x 1152 bf16
  size_t off = (size_t)NBATCH * KFIN * sizeof(__hip_bfloat16);    // 75.5 MB
  float* H = (float*)(ws + off);    off += (size_t)1024 * 1024 * 4;
  float* Pm = (float*)(ws + off);   off += (size_t)512 * 512 * 4;
  float* D11 = (float*)(ws + off);  off += (size_t)512 * 512 * 4;
  float* C1 = (float*)(ws + off);   off += (size_t)512 * 512 * 4;
  float* Wm = (float*)(ws + off);   off += (size_t)512 * 1024 * 4;
  __hip_bfloat16* Wbase = (__hip_bfloat16*)(ws + off); off += (size_t)512 * KBASE * 2;
  __hip_bfloat16* Wfin = (__hip_bfloat16*)(ws + off);  off += (size_t)512 * KFIN * 2;

  // ---- pack Z (xi|u) in bf16 ----
  k_pack_z<<<NBATCH, 256, 0, stream>>>(xi, u, Zb);

  // ---- small-matrix stage (fp32) ----
  k_syrk<<<dim3(16, 16), 256, 0, stream>>>(X, H, 1024, 1024, 1.0f);
  k_syrk<<<dim3(8, 8), 256, 0, stream>>>(Pstar, Pm, 512, 512, 0.5f);
  k_prep<<<512, 256, 0, stream>>>(H, Y1, Chi, D11, C1, Wm);

  for (int kb = 0; kb < 4; ++kb) {
    k_chol_diag<<<1, 256, 0, stream>>>(Pm, kb);
    int rem = 512 - (kb + 1) * 128;
    if (rem > 0) {
      k_trsm<<<rem / 128, 128, 0, stream>>>(Pm, kb);
      k_gemm_acc<0, 1><<<dim3(rem / 64, rem / 64), 256, 0, stream>>>(
          Pm, 512, (kb + 1) * 128, (kb + 1) * 128,
          Pm, 512, (kb + 1) * 128,
          Pm, 512, (kb + 1) * 128, kb * 128, 128);
    }
  }
  for (int kb = 0; kb < 4; ++kb) {
    k_solve_f<<<4, 256, 0, stream>>>(Pm, Wm, kb);
    int rem = 512 - (kb + 1) * 128;
    if (rem > 0)
      k_gemm_acc<0, 0><<<dim3(rem / 64, 16), 256, 0, stream>>>(
          Wm, 1024, (kb + 1) * 128, 0,
          Pm, 512, (kb + 1) * 128,
          Wm, 1024, 0, kb * 128, 128);
  }
  for (int kb = 3; kb >= 0; --kb) {
    k_solve_b<<<4, 256, 0, stream>>>(Pm, Wm, kb);
    if (kb > 0)
      k_gemm_acc<1, 0><<<dim3(kb * 128 / 64, 16), 256, 0, stream>>>(
          Wm, 1024, 0, 0,
          Pm, 512, 0,
          Wm, 1024, 0, kb * 128, 128);
  }

  // ---- pack weights in bf16 ----
  k_pack_w<<<512, 256, 0, stream>>>(C1, D12, Wm, B2, Wbase, Wfin);

  // ---- big stage (bf16 MFMA) ----
  // base = Z[:, :640] @ Wbase^T  -> d_out used as fp32 scratch
  k_gemm_bf16<<<dim3(NBATCH / 128, NQD / 128), 256, 0, stream>>>(
      (const u16*)Zb, KFIN, (const u16*)Wbase, KBASE, out, NQD, KBASE);
  // sequential tanh recurrence -> w (bf16) into Z[:, 640:1152]
  k_scan<<<NBATCH / 32, 512, 0, stream>>>(out, D11, Zb + KBASE);
  // xi_ = Z @ Wfin^T
  k_gemm_bf16<<<dim3(NBATCH / 128, NXD / 128), 256, 0, stream>>>(
      (const u16*)Zb, KFIN, (const u16*)Wfin, KFIN, out, NXD, KFIN);
}

// Round 4
// 1616.285 us; speedup vs baseline: 4.0251x; 3.5746x over previous
//
#include <hip/hip_runtime.h>
#include <hip/hip_bf16.h>
#include <cstdint>
#include <cstddef>

// Problem constants
#define NXD 512
#define NQD 512
#define NUD 128
#define NBATCH 32768
#define EPSV 1e-3f
#define KBASE 640   // [xi | u]
#define KFIN 1152   // [xi | u | w]

typedef unsigned short u16;
typedef short bf16x8 __attribute__((ext_vector_type(8)));
typedef _Float16 f16x8 __attribute__((ext_vector_type(8)));
typedef float f32x4 __attribute__((ext_vector_type(4)));

__device__ __forceinline__ void gload_lds16(const u16* g, u16* l) {
  __builtin_amdgcn_global_load_lds((const __attribute__((address_space(1))) void*)g,
                                   (__attribute__((address_space(3))) void*)l, 16, 0, 0);
}

__device__ __forceinline__ float fast_tanh(float x) {
  float e = __expf(2.0f * x);
  return 1.0f - 2.0f / (e + 1.0f);
}

// ---------------------------------------------------------------------------
// k_syrk: C = scale * A @ A^T + EPS*I      A: N x K row-major (lda=K), C: NxN
// ---------------------------------------------------------------------------
__global__ __launch_bounds__(256) void k_syrk(const float* __restrict__ A,
                                              float* __restrict__ C,
                                              int N, int K, float scale) {
  __shared__ float As[16][68];
  __shared__ float Bs[16][68];
  int tid = threadIdx.x;
  int row = tid >> 2;
  int q4 = (tid & 3) * 4;
  int tx = tid & 15, ty = tid >> 4;
  int i0 = blockIdx.x * 64, j0 = blockIdx.y * 64;
  float acc[4][4] = {};
  for (int k0 = 0; k0 < K; k0 += 16) {
    float4 a = *(const float4*)&A[(size_t)(i0 + row) * K + k0 + q4];
    float4 b = *(const float4*)&A[(size_t)(j0 + row) * K + k0 + q4];
    __syncthreads();
    As[q4 + 0][row] = a.x; As[q4 + 1][row] = a.y; As[q4 + 2][row] = a.z; As[q4 + 3][row] = a.w;
    Bs[q4 + 0][row] = b.x; Bs[q4 + 1][row] = b.y; Bs[q4 + 2][row] = b.z; Bs[q4 + 3][row] = b.w;
    __syncthreads();
#pragma unroll
    for (int kk = 0; kk < 16; ++kk) {
      float av[4], bv[4];
      *(float4*)av = *(const float4*)&As[kk][ty * 4];
      *(float4*)bv = *(const float4*)&Bs[kk][tx * 4];
#pragma unroll
      for (int i = 0; i < 4; ++i)
#pragma unroll
        for (int j = 0; j < 4; ++j) acc[i][j] += av[i] * bv[j];
    }
  }
#pragma unroll
  for (int i = 0; i < 4; ++i)
#pragma unroll
    for (int j = 0; j < 4; ++j) {
      int r = i0 + ty * 4 + i, c = j0 + tx * 4 + j;
      float v = acc[i][j] * scale;
      if (r == c) v += EPSV;
      C[(size_t)r * N + c] = v;
    }
}

// ---------------------------------------------------------------------------
// k_prep: lam, D11, C1, RHS(=[Y | -H2-Chi]) from H, Y1, Chi
// ---------------------------------------------------------------------------
__global__ void k_prep(const float* __restrict__ H, const float* __restrict__ Y1,
                       const float* __restrict__ Chi, float* __restrict__ D11,
                       float* __restrict__ C1, float* __restrict__ RHS) {
  int i = blockIdx.x;  // 0..511
  float lam = 0.5f * H[(size_t)(512 + i) * 1024 + 512 + i];
  float rlam = 1.0f / lam;
  for (int j = threadIdx.x; j < 512; j += blockDim.x) {
    float h4 = H[(size_t)(512 + i) * 1024 + 512 + j];
    D11[i * 512 + j] = (j < i) ? (-h4 * rlam) : 0.0f;
    C1[i * 512 + j] = Chi[(size_t)j * 512 + i] * rlam;
    float y = -0.5f * (H[(size_t)i * 1024 + j] + Y1[(size_t)i * 512 + j] - Y1[(size_t)j * 512 + i]);
    RHS[(size_t)i * 1024 + j] = y;
    RHS[(size_t)i * 1024 + 512 + j] = -H[(size_t)i * 1024 + 512 + j] - Chi[(size_t)i * 512 + j];
  }
}

// ---------------------------------------------------------------------------
// k_chol_diag64: factor 64x64 diagonal block of P in place (NB=64).
// ---------------------------------------------------------------------------
__global__ __launch_bounds__(256) void k_chol_diag64(float* __restrict__ P, int kb) {
  __shared__ float colbuf[2][72];
  int tid = threadIdx.x;
  int ty = tid >> 4, tx = tid & 15;
  int base = kb * 64;
  float T[4][4];
#pragma unroll
  for (int rr = 0; rr < 4; ++rr)
#pragma unroll
    for (int cc = 0; cc < 4; ++cc)
      T[rr][cc] = P[(size_t)(base + ty * 4 + rr) * 512 + base + tx * 4 + cc];

  for (int c = 0; c < 64; ++c) {
    float* cb = colbuf[c & 1];
    if (tx == (c >> 2)) {
      int cc = c & 3;
#pragma unroll
      for (int rr = 0; rr < 4; ++rr) cb[ty * 4 + rr] = T[rr][cc];
    }
    __syncthreads();
    float dcv = cb[c];
    float dc = sqrtf(dcv);
    float rdc = 1.0f / dc;
    float rdcv = 1.0f / dcv;
    if (tx == (c >> 2)) {
      int cc = c & 3;
#pragma unroll
      for (int rr = 0; rr < 4; ++rr) {
        int r = ty * 4 + rr;
        if (r == c) T[rr][cc] = dc;
        else if (r > c) T[rr][cc] *= rdc;
      }
    }
    float cr[4], cj[4];
#pragma unroll
    for (int rr = 0; rr < 4; ++rr) {
      int r = ty * 4 + rr;
      cr[rr] = (r > c) ? cb[r] * rdcv : 0.0f;
    }
#pragma unroll
    for (int cc = 0; cc < 4; ++cc) {
      int j = tx * 4 + cc;
      cj[cc] = (j > c) ? cb[j] : 0.0f;
    }
#pragma unroll
    for (int rr = 0; rr < 4; ++rr)
#pragma unroll
      for (int cc = 0; cc < 4; ++cc) T[rr][cc] -= cr[rr] * cj[cc];
  }
  __syncthreads();
#pragma unroll
  for (int rr = 0; rr < 4; ++rr)
#pragma unroll
    for (int cc = 0; cc < 4; ++cc)
      P[(size_t)(base + ty * 4 + rr) * 512 + base + tx * 4 + cc] = T[rr][cc];
}

// ---------------------------------------------------------------------------
// k_trsm64: panel solve L21 = A21 * inv(L11^T), NB=64. One thread per row.
// ---------------------------------------------------------------------------
__global__ __launch_bounds__(256) void k_trsm64(float* __restrict__ P, int kb, int rem) {
  __shared__ float Ls[64 * 64];
  int tid = threadIdx.x;
  int base = kb * 64;
  for (int idx = tid; idx < 64 * 64; idx += 256) {
    int r = idx >> 6, c = idx & 63;
    Ls[idx] = P[(size_t)(base + r) * 512 + base + c];
  }
  __syncthreads();
  int ir = blockIdx.x * 256 + tid;
  if (ir >= rem) return;
  int i = base + 64 + ir;
  float x[64];
  float* Arow = &P[(size_t)i * 512 + base];
#pragma unroll
  for (int c = 0; c < 64; ++c) {
    float a0 = Arow[c], a1 = 0.f, a2 = 0.f, a3 = 0.f;
#pragma unroll
    for (int m = 0; m < c; m += 4) {
      a0 -= x[m] * Ls[c * 64 + m];
      if (m + 1 < c) a1 -= x[m + 1] * Ls[c * 64 + m + 1];
      if (m + 2 < c) a2 -= x[m + 2] * Ls[c * 64 + m + 2];
      if (m + 3 < c) a3 -= x[m + 3] * Ls[c * 64 + m + 3];
    }
    x[c] = ((a0 + a1) + (a2 + a3)) / Ls[c * 64 + c];
  }
#pragma unroll
  for (int c = 0; c < 64; ++c) Arow[c] = x[c];
}

// ---------------------------------------------------------------------------
// k_solve_f64 / k_solve_b64: 64x64 diagonal-block triangular solves on
// W (512 x 1024). One thread per RHS column, z[64] in registers.
// ---------------------------------------------------------------------------
__global__ __launch_bounds__(256) void k_solve_f64(const float* __restrict__ P,
                                                   float* __restrict__ W, int kb) {
  __shared__ float Ls[64 * 64];
  int tid = threadIdx.x;
  int base = kb * 64;
  int c = blockIdx.x * 256 + tid;
  for (int idx = tid; idx < 64 * 64; idx += 256) {
    int r = idx >> 6, m = idx & 63;
    Ls[idx] = P[(size_t)(base + r) * 512 + base + m];
  }
  __syncthreads();
  float z[64];
#pragma unroll
  for (int r = 0; r < 64; ++r) {
    float a0 = W[(size_t)(base + r) * 1024 + c], a1 = 0.f, a2 = 0.f, a3 = 0.f;
#pragma unroll
    for (int m = 0; m < r; m += 4) {
      a0 -= z[m] * Ls[r * 64 + m];
      if (m + 1 < r) a1 -= z[m + 1] * Ls[r * 64 + m + 1];
      if (m + 2 < r) a2 -= z[m + 2] * Ls[r * 64 + m + 2];
      if (m + 3 < r) a3 -= z[m + 3] * Ls[r * 64 + m + 3];
    }
    z[r] = ((a0 + a1) + (a2 + a3)) / Ls[r * 64 + r];
  }
#pragma unroll
  for (int r = 0; r < 64; ++r) W[(size_t)(base + r) * 1024 + c] = z[r];
}

__global__ __launch_bounds__(256) void k_solve_b64(const float* __restrict__ P,
                                                   float* __restrict__ W, int kb) {
  __shared__ float LsT[64 * 64];  // LsT[r][m] = L[m][r]
  int tid = threadIdx.x;
  int base = kb * 64;
  int c = blockIdx.x * 256 + tid;
  for (int idx = tid; idx < 64 * 64; idx += 256) {
    int r = idx >> 6, m = idx & 63;
    LsT[idx] = P[(size_t)(base + m) * 512 + base + r];
  }
  __syncthreads();
  float z[64];
#pragma unroll
  for (int rr = 0; rr < 64; ++rr) {
    int r = 63 - rr;
    float a0 = W[(size_t)(base + r) * 1024 + c], a1 = 0.f, a2 = 0.f, a3 = 0.f;
#pragma unroll
    for (int m = r + 1; m < 64; m += 4) {
      a0 -= z[m] * LsT[r * 64 + m];
      if (m + 1 < 64) a1 -= z[m + 1] * LsT[r * 64 + m + 1];
      if (m + 2 < 64) a2 -= z[m + 2] * LsT[r * 64 + m + 2];
      if (m + 3 < 64) a3 -= z[m + 3] * LsT[r * 64 + m + 3];
    }
    z[r] = ((a0 + a1) + (a2 + a3)) / LsT[r * 64 + r];
  }
#pragma unroll
  for (int r = 0; r < 64; ++r) W[(size_t)(base + r) * 1024 + c] = z[r];
}

// ---------------------------------------------------------------------------
// k_gemm_acc<TA,TB>: C -= Aop @ Bop (trailing updates, fp32, small matrices)
// ---------------------------------------------------------------------------
template <int TA, int TB>
__global__ __launch_bounds__(256) void k_gemm_acc(float* __restrict__ C, int ldc,
                                                  int ci0, int cj0,
                                                  const float* __restrict__ A, int lda, int ai0,
                                                  const float* __restrict__ B, int ldb, int bj0,
                                                  int k0, int K) {
  __shared__ float As[16][68];
  __shared__ float Bs[16][68];
  int tid = threadIdx.x;
  int tx = tid & 15, ty = tid >> 4;
  int i0 = blockIdx.x * 64, j0 = blockIdx.y * 64;
  float acc[4][4] = {};
  for (int kc = 0; kc < K; kc += 16) {
    float4 av, bv;
    if (TA == 0) {
      int row = tid >> 2, q4 = (tid & 3) * 4;
      av = *(const float4*)&A[(size_t)(ai0 + i0 + row) * lda + k0 + kc + q4];
    } else {
      int kr = tid >> 4, m4 = (tid & 15) * 4;
      av = *(const float4*)&A[(size_t)(k0 + kc + kr) * lda + ai0 + i0 + m4];
    }
    if (TB == 0) {
      int kr = tid >> 4, j4 = (tid & 15) * 4;
      bv = *(const float4*)&B[(size_t)(k0 + kc + kr) * ldb + bj0 + j0 + j4];
    } else {
      int row = tid >> 2, q4 = (tid & 3) * 4;
      bv = *(const float4*)&B[(size_t)(bj0 + j0 + row) * ldb + k0 + kc + q4];
    }
    __syncthreads();
    if (TA == 0) {
      int row = tid >> 2, q4 = (tid & 3) * 4;
      As[q4 + 0][row] = av.x; As[q4 + 1][row] = av.y; As[q4 + 2][row] = av.z; As[q4 + 3][row] = av.w;
    } else {
      int kr = tid >> 4, m4 = (tid & 15) * 4;
      *(float4*)&As[kr][m4] = av;
    }
    if (TB == 0) {
      int kr = tid >> 4, j4 = (tid & 15) * 4;
      *(float4*)&Bs[kr][j4] = bv;
    } else {
      int row = tid >> 2, q4 = (tid & 3) * 4;
      Bs[q4 + 0][row] = bv.x; Bs[q4 + 1][row] = bv.y; Bs[q4 + 2][row] = bv.z; Bs[q4 + 3][row] = bv.w;
    }
    __syncthreads();
#pragma unroll
    for (int kk = 0; kk < 16; ++kk) {
      float a4[4], b4[4];
      *(float4*)a4 = *(const float4*)&As[kk][ty * 4];
      *(float4*)b4 = *(const float4*)&Bs[kk][tx * 4];
#pragma unroll
      for (int i = 0; i < 4; ++i)
#pragma unroll
        for (int j = 0; j < 4; ++j) acc[i][j] += a4[i] * b4[j];
    }
  }
#pragma unroll
  for (int i = 0; i < 4; ++i)
#pragma unroll
    for (int j = 0; j < 4; ++j)
      C[(size_t)(ci0 + i0 + ty * 4 + i) * ldc + cj0 + j0 + tx * 4 + j] -= acc[i][j];
}

// ---------------------------------------------------------------------------
// k_pack_z: Zb[b][0:512) = bf16(xi[b]), Zb[b][512:640) = bf16(u[b])
// ---------------------------------------------------------------------------
__global__ __launch_bounds__(256) void k_pack_z(const float* __restrict__ xi,
                                                const float* __restrict__ u,
                                                __hip_bfloat16* __restrict__ Zb) {
  size_t b = blockIdx.x;
  for (int c = threadIdx.x; c < KBASE; c += 256) {
    float v = (c < 512) ? xi[b * 512 + c] : u[b * 128 + (c - 512)];
    Zb[b * KFIN + c] = __float2bfloat16(v);
  }
}

// ---------------------------------------------------------------------------
// k_pack_w: Wbase[n] = [C1[n,:] | D12[n,:]]  (512 x 640)
//           Wfin[n]  = [A[n,:] | B2[n,:] | B1[n,:]]  (512 x 1152)
//           D11h = fp16(D11)  (512 x 512, for the scan bulk MFMA)
// ---------------------------------------------------------------------------
__global__ __launch_bounds__(256) void k_pack_w(const float* __restrict__ C1,
                                                const float* __restrict__ D12,
                                                const float* __restrict__ Wm,
                                                const float* __restrict__ B2,
                                                const float* __restrict__ D11,
                                                __hip_bfloat16* __restrict__ Wbase,
                                                __hip_bfloat16* __restrict__ Wfin,
                                                u16* __restrict__ D11h) {
  int n = blockIdx.x;
  for (int c = threadIdx.x; c < KBASE; c += 256) {
    float v = (c < 512) ? C1[(size_t)n * 512 + c] : D12[(size_t)n * 128 + (c - 512)];
    Wbase[(size_t)n * KBASE + c] = __float2bfloat16(v);
  }
  for (int c = threadIdx.x; c < KFIN; c += 256) {
    float v;
    if (c < 512) v = Wm[(size_t)n * 1024 + c];                 // A
    else if (c < 640) v = B2[(size_t)n * 128 + (c - 512)];     // B2
    else v = Wm[(size_t)n * 1024 + 512 + (c - 640)];           // B1
    Wfin[(size_t)n * KFIN + c] = __float2bfloat16(v);
  }
  for (int c = threadIdx.x; c < 512; c += 256) {
    _Float16 h = (_Float16)D11[(size_t)n * 512 + c];
    D11h[(size_t)n * 512 + c] = *(u16*)&h;
  }
}

// ---------------------------------------------------------------------------
// k_gemm_bf16: C[m][n] = sum_k Z[m][k] * W[n][k]   (both K-contiguous rows)
// 128x128 tile, BK=32, 256 threads = 4 waves in 2x2, 16x16x32 bf16 MFMA.
// ---------------------------------------------------------------------------
__global__ __launch_bounds__(256) void k_gemm_bf16(
    const u16* __restrict__ Z, int ldz,
    const u16* __restrict__ W, int ldw,
    float* __restrict__ C, int N, int K) {
  __shared__ u16 As[128 * 32];
  __shared__ u16 Bs[128 * 32];
  int tid = threadIdx.x;
  int l = tid & 63, wv = tid >> 6;
  size_t m0 = (size_t)blockIdx.x * 128;
  int n0 = blockIdx.y * 128;

  int ra = wv * 16 + (l >> 2);
  int gq = (l & 3) ^ ((l >> 2) & 3) ^ (l >> 4);
  const u16* ga0 = Z + (m0 + ra) * (size_t)ldz + gq * 8;
  const u16* ga1 = Z + (m0 + ra + 64) * (size_t)ldz + gq * 8;
  const u16* gb0 = W + (size_t)(n0 + ra) * ldw + gq * 8;
  const u16* gb1 = W + (size_t)(n0 + ra + 64) * ldw + gq * 8;
  u16* la0 = &As[wv * 512];
  u16* la1 = &As[2048 + wv * 512];
  u16* lb0 = &Bs[wv * 512];
  u16* lb1 = &Bs[2048 + wv * 512];

  int wm = (wv & 1) * 64, wn = (wv >> 1) * 64;
  int fr = l & 15;
  int fs = (l >> 4) ^ (l & 3) ^ ((l >> 2) & 3);
  int offa[4], offb[4];
#pragma unroll
  for (int t = 0; t < 4; ++t) {
    offa[t] = (wm + t * 16 + fr) * 32 + fs * 8;
    offb[t] = (wn + t * 16 + fr) * 32 + fs * 8;
  }

  f32x4 acc[4][4] = {};
  for (int k0 = 0; k0 < K; k0 += 32) {
    __syncthreads();
    gload_lds16(ga0, la0);
    gload_lds16(ga1, la1);
    gload_lds16(gb0, lb0);
    gload_lds16(gb1, lb1);
    ga0 += 32; ga1 += 32; gb0 += 32; gb1 += 32;
    __syncthreads();
    bf16x8 af[4], bfr[4];
#pragma unroll
    for (int t = 0; t < 4; ++t) {
      af[t] = *(const bf16x8*)&As[offa[t]];
      bfr[t] = *(const bf16x8*)&Bs[offb[t]];
    }
#pragma unroll
    for (int mt = 0; mt < 4; ++mt)
#pragma unroll
      for (int nt = 0; nt < 4; ++nt)
        acc[mt][nt] = __builtin_amdgcn_mfma_f32_16x16x32_bf16(af[mt], bfr[nt], acc[mt][nt], 0, 0, 0);
  }

#pragma unroll
  for (int mt = 0; mt < 4; ++mt)
#pragma unroll
    for (int nt = 0; nt < 4; ++nt) {
      int ncol = n0 + wn + nt * 16 + (l & 15);
#pragma unroll
      for (int r = 0; r < 4; ++r) {
        size_t mrow = m0 + wm + mt * 16 + (l >> 4) * 4 + r;
        C[mrow * N + ncol] = acc[mt][nt][r];
      }
    }
}

// ---------------------------------------------------------------------------
// k_scan_mfma: chunked recurrence, 32 chunks of 16.
// Bulk (j < i0) via fp16 16x16x32 MFMA: full 32-blocks + masked 16-remainder
// for odd chunks (this fixes the round-3 dropped-chunk bug).
// w kept as fp16 in LDS (2^-11 quantization: recurrence ~fp32-accurate);
// in-chunk 16 serial steps in fp32. 4 independent waves, NO barriers.
// ---------------------------------------------------------------------------
#define WSTR 520  // u16 row stride (1040 B, 16B-aligned)
__global__ __launch_bounds__(256) void k_scan_mfma(
    const float* __restrict__ basep,    // 32768 x 512 fp32
    const float* __restrict__ D11,      // 512 x 512 fp32
    const u16* __restrict__ D11h,       // 512 x 512 fp16
    u16* __restrict__ zw) {             // Zb + 640, row stride KFIN (bf16)
  __shared__ u16 wbf_s[4][16 * WSTR];
  __shared__ float ptr_s[4][16 * 16];
  __shared__ float dls_s[4][16 * 16];

  int tid = threadIdx.x;
  int wv = tid >> 6, l = tid & 63;
  int r = l & 15;   // row-in-tile (A m-index for bulk / batch row for serial)
  int q = l >> 4;   // 0..3 (k-chunk for frags / residue lane for serial)
  size_t gm0 = (size_t)blockIdx.x * 64 + wv * 16;

  u16* wbf = wbf_s[wv];
  float* ptr = ptr_s[wv];
  float* dls = dls_s[wv];

  float wreg[4] = {0.f, 0.f, 0.f, 0.f};

  for (int c = 0; c < 32; ++c) {
    int i0 = c * 16;
    int nk = i0 >> 5;          // full 32-wide history blocks (wave-uniform)
    int rem = c & 1;           // 16-col remainder block present?
    // ---- batched B-frag loads for the whole chunk (independent, pipelined)
    const u16* drow = &D11h[(size_t)(i0 + r) * 512 + q * 8];
    f16x8 bfr[16];
#pragma unroll
    for (int k = 0; k < 16; ++k)
      if (k < nk) bfr[k] = *(const f16x8*)&drow[k * 32];
    f16x8 brem = {};
    if (rem && q < 2) brem = *(const f16x8*)&drow[nk * 32];
    // ---- stage D11 diag block (fp32) into dls: lane covers (q+4k, r)
#pragma unroll
    for (int k = 0; k < 4; ++k) {
      int ii = q + 4 * k;
      dls[ii * 16 + r] = D11[(size_t)(i0 + ii) * 512 + i0 + r];
    }
    // ---- bulk MFMA chain: acc(16x16) = w[:, :i0] @ D11[i0:i0+16, :i0]^T
    f32x4 acc = {0.f, 0.f, 0.f, 0.f};
#pragma unroll
    for (int k = 0; k < 16; ++k)
      if (k < nk) {
        f16x8 a = *(const f16x8*)&wbf[r * WSTR + k * 32 + q * 8];
        acc = __builtin_amdgcn_mfma_f32_16x16x32_f16(a, bfr[k], acc, 0, 0, 0);
      }
    if (rem) {
      f16x8 a = {};
      if (q < 2) a = *(const f16x8*)&wbf[r * WSTR + nk * 32 + q * 8];
      acc = __builtin_amdgcn_mfma_f32_16x16x32_f16(a, brem, acc, 0, 0, 0);
    }
    // ---- add base (C layout: col=r, rows q*4+reg)
#pragma unroll
    for (int reg = 0; reg < 4; ++reg)
      acc[reg] += basep[(gm0 + q * 4 + reg) * 512 + i0 + r];
    // ---- transpose via LDS (quad-xor swizzle on 4-col chunks)
#pragma unroll
    for (int reg = 0; reg < 4; ++reg) {
      int m = q * 4 + reg;
      int nsw = r ^ ((m & 3) << 2);
      ptr[m * 16 + nsw] = acc[reg];
    }
    float p[16];
#pragma unroll
    for (int j = 0; j < 4; ++j) {
      float4 v4 = *(const float4*)&ptr[r * 16 + j * 4];
      int cj = (j ^ (r & 3)) * 4;
      p[cj + 0] = v4.x; p[cj + 1] = v4.y; p[cj + 2] = v4.z; p[cj + 3] = v4.w;
    }
    // ---- serial 16 steps (batch row r, 4 lanes with residue q)
#pragma unroll
    for (int s = 0; s < 16; ++s) {
      float prod = 0.f;
#pragma unroll
      for (int m = 0; m < 4; ++m)
        prod = fmaf(wreg[m], dls[s * 16 + q + 4 * m], prod);  // D11=0 for t>=s
      prod += __shfl_xor(prod, 16);
      prod += __shfl_xor(prod, 32);
      float w = fast_tanh(p[s] + prod);
      if ((s & 3) == q) {
        wreg[s >> 2] = w;
        *(_Float16*)&wbf[r * WSTR + i0 + s] = (_Float16)w;
      }
    }
  }
  // ---- epilogue: wbf (fp16) -> Zb w-region (bf16, coalesced 16B stores)
#pragma unroll
  for (int it = 0; it < 16; ++it) {
    int idx = it * 64 + l;
    int row = idx >> 6;
    int ch = idx & 63;
    f16x8 v = *(const f16x8*)&wbf[row * WSTR + ch * 8];
    u16 o[8];
#pragma unroll
    for (int e = 0; e < 8; ++e) {
      __hip_bfloat16 b = __float2bfloat16((float)v[e]);
      o[e] = *(u16*)&b;
    }
    *(uint4*)&zw[(gm0 + row) * KFIN + ch * 8] = *(const uint4*)o;
  }
}

// ---------------------------------------------------------------------------
extern "C" void kernel_launch(void* const* d_in, const int* in_sizes, int n_in,
                              void* d_out, int out_size, void* d_ws, size_t ws_size,
                              hipStream_t stream) {
  const float* xi = (const float*)d_in[1];
  const float* u = (const float*)d_in[2];
  const float* Pstar = (const float*)d_in[3];
  const float* Chi = (const float*)d_in[4];
  const float* Y1 = (const float*)d_in[5];
  const float* B2 = (const float*)d_in[6];
  const float* D12 = (const float*)d_in[7];
  const float* X = (const float*)d_in[8];
  float* out = (float*)d_out;

  char* ws = (char*)d_ws;
  __hip_bfloat16* Zb = (__hip_bfloat16*)ws;                       // 32768 x 1152 bf16
  size_t off = (size_t)NBATCH * KFIN * sizeof(__hip_bfloat16);
  float* H = (float*)(ws + off);    off += (size_t)1024 * 1024 * 4;
  float* Pm = (float*)(ws + off);   off += (size_t)512 * 512 * 4;
  float* D11 = (float*)(ws + off);  off += (size_t)512 * 512 * 4;
  float* C1 = (float*)(ws + off);   off += (size_t)512 * 512 * 4;
  float* Wm = (float*)(ws + off);   off += (size_t)512 * 1024 * 4;
  __hip_bfloat16* Wbase = (__hip_bfloat16*)(ws + off); off += (size_t)512 * KBASE * 2;
  __hip_bfloat16* Wfin = (__hip_bfloat16*)(ws + off);  off += (size_t)512 * KFIN * 2;
  u16* D11h = (u16*)(ws + off);                        off += (size_t)512 * 512 * 2;

  // ---- pack Z (xi|u) in bf16 ----
  k_pack_z<<<NBATCH, 256, 0, stream>>>(xi, u, Zb);

  // ---- small-matrix stage (fp32, NB=64 blocking) ----
  k_syrk<<<dim3(16, 16), 256, 0, stream>>>(X, H, 1024, 1024, 1.0f);
  k_syrk<<<dim3(8, 8), 256, 0, stream>>>(Pstar, Pm, 512, 512, 0.5f);
  k_prep<<<512, 256, 0, stream>>>(H, Y1, Chi, D11, C1, Wm);

  for (int kb = 0; kb < 8; ++kb) {
    k_chol_diag64<<<1, 256, 0, stream>>>(Pm, kb);
    int rem = 512 - (kb + 1) * 64;
    if (rem > 0) {
      k_trsm64<<<(rem + 255) / 256, 256, 0, stream>>>(Pm, kb, rem);
      k_gemm_acc<0, 1><<<dim3(rem / 64, rem / 64), 256, 0, stream>>>(
          Pm, 512, (kb + 1) * 64, (kb + 1) * 64,
          Pm, 512, (kb + 1) * 64,
          Pm, 512, (kb + 1) * 64, kb * 64, 64);
    }
  }
  for (int kb = 0; kb < 8; ++kb) {
    k_solve_f64<<<4, 256, 0, stream>>>(Pm, Wm, kb);
    int rem = 512 - (kb + 1) * 64;
    if (rem > 0)
      k_gemm_acc<0, 0><<<dim3(rem / 64, 16), 256, 0, stream>>>(
          Wm, 1024, (kb + 1) * 64, 0,
          Pm, 512, (kb + 1) * 64,
          Wm, 1024, 0, kb * 64, 64);
  }
  for (int kb = 7; kb >= 0; --kb) {
    k_solve_b64<<<4, 256, 0, stream>>>(Pm, Wm, kb);
    if (kb > 0)
      k_gemm_acc<1, 0><<<dim3(kb, 16), 256, 0, stream>>>(
          Wm, 1024, 0, 0,
          Pm, 512, 0,
          Wm, 1024, 0, kb * 64, 64);
  }

  // ---- pack weights + D11h ----
  k_pack_w<<<512, 256, 0, stream>>>(C1, D12, Wm, B2, D11, Wbase, Wfin, D11h);

  // ---- big stage (bf16 MFMA) ----
  k_gemm_bf16<<<dim3(NBATCH / 128, NQD / 128), 256, 0, stream>>>(
      (const u16*)Zb, KFIN, (const u16*)Wbase, KBASE, out, NQD, KBASE);
  k_scan_mfma<<<NBATCH / 64, 256, 0, stream>>>(out, D11, D11h, (u16*)(Zb + KBASE));
  k_gemm_bf16<<<dim3(NBATCH / 128, NXD / 128), 256, 0, stream>>>(
      (const u16*)Zb, KFIN, (const u16*)Wfin, KFIN, out, NXD, KFIN);
}